// Round 1
// baseline (403.756 us; speedup 1.0000x reference)
//
#include <hip/hip_runtime.h>
#include <math.h>

#define B_DIM 8
#define C_DIM 32
#define N_DIM 4096
#define TM 64      // output columns per block
#define NK 32      // k-chunk
#define BLOCK 128  // threads per block

// Kernel 1: c_adj[b,n] = mean over channels of x[b,c,n]
__global__ __launch_bounds__(256) void channel_mean_kernel(
    const float* __restrict__ x, float* __restrict__ cadj) {
  int idx = blockIdx.x * blockDim.x + threadIdx.x;
  if (idx >= B_DIM * N_DIM) return;
  int b = idx >> 12;            // / N_DIM
  int n = idx & (N_DIM - 1);
  const float* p = x + (size_t)b * C_DIM * N_DIM + n;
  float s = 0.f;
#pragma unroll
  for (int c = 0; c < C_DIM; ++c) s += p[(size_t)c * N_DIM];
  cadj[idx] = s * (1.0f / C_DIM);
}

// Kernel 2: out[b,c,m] = relu( para[c,m] * sum_n fea[b,c,n] * adj[n,m] * w(b,n,m) )
// w = 2*sigmoid(-|c_adj[b,n]-c_adj[b,m]|)  (even in d => symmetrization is identity)
__global__ __launch_bounds__(BLOCK) void gcn_fused_kernel(
    const float* __restrict__ x, const float* __restrict__ para,
    const float* __restrict__ adj, const float* __restrict__ cadj,
    float* __restrict__ out) {
  // fea_s padded to 36 floats/row: 16B-aligned float4 rows, mild store conflicts only
  __shared__ __align__(16) float fea_s[NK][C_DIM + 4];
  __shared__ __align__(16) float w_s[NK][TM];
  __shared__ float cadjm_s[TM];

  const int b = blockIdx.y;
  const int m0 = blockIdx.x * TM;
  const int tid = threadIdx.x;
  const int tx = tid & 15;   // m sub-tile: columns m0 + tx*4 .. +3
  const int ty = tid >> 4;   // c sub-tile: channels ty*4 .. +3

  if (tid < TM) cadjm_s[tid] = cadj[b * N_DIM + m0 + tid];

  float acc[4][4] = {};

  for (int k0 = 0; k0 < N_DIM; k0 += NK) {
    __syncthreads();  // previous main loop done reading LDS (also covers cadjm_s init)

    // Stage fea[b, 0:32, k0:k0+NK] into LDS as [n][c]
#pragma unroll
    for (int i = 0; i < (NK * C_DIM) / BLOCK; ++i) {
      int e = i * BLOCK + tid;
      int n = e & (NK - 1);
      int c = e >> 5;  // / NK
      fea_s[n][c] = x[((size_t)(b * C_DIM + c)) * N_DIM + k0 + n];
    }

    // Cooperatively compute weight tile W[n][m] = adj * 2t/(1+t)
#pragma unroll
    for (int i = 0; i < (NK * TM) / BLOCK; ++i) {
      int e = i * BLOCK + tid;
      int n = e >> 6;          // / TM
      int m = e & (TM - 1);
      float a = adj[(size_t)(k0 + n) * N_DIM + m0 + m];
      float d = cadj[b * N_DIM + k0 + n] - cadjm_s[m];
      float t = __expf(-fabsf(d));
      float w = a * (2.0f * t * __builtin_amdgcn_rcpf(1.0f + t));
      w_s[n][m] = w;
    }

    __syncthreads();

    // Register-tiled inner product: 4 channels x 4 columns per thread
#pragma unroll
    for (int n = 0; n < NK; ++n) {
      const float4 f = *(const float4*)(&fea_s[n][ty * 4]);
      const float4 wv = *(const float4*)(&w_s[n][tx * 4]);
      float fr[4] = {f.x, f.y, f.z, f.w};
      float wr[4] = {wv.x, wv.y, wv.z, wv.w};
#pragma unroll
      for (int i = 0; i < 4; ++i)
#pragma unroll
        for (int j = 0; j < 4; ++j) acc[i][j] += fr[i] * wr[j];
    }
  }

  // Epilogue: * para, relu, vectorized store
#pragma unroll
  for (int i = 0; i < 4; ++i) {
    int c = ty * 4 + i;
    int mcol = m0 + tx * 4;
    const float4 p = *(const float4*)(&para[(size_t)c * N_DIM + mcol]);
    float4 o;
    o.x = fmaxf(acc[i][0] * p.x, 0.0f);
    o.y = fmaxf(acc[i][1] * p.y, 0.0f);
    o.z = fmaxf(acc[i][2] * p.z, 0.0f);
    o.w = fmaxf(acc[i][3] * p.w, 0.0f);
    *(float4*)(&out[((size_t)(b * C_DIM + c)) * N_DIM + mcol]) = o;
  }
}

extern "C" void kernel_launch(void* const* d_in, const int* in_sizes, int n_in,
                              void* d_out, int out_size, void* d_ws, size_t ws_size,
                              hipStream_t stream) {
  const float* x = (const float*)d_in[0];     // [8,32,64,64]
  const float* para = (const float*)d_in[1];  // [1,32,64,64]
  const float* adj = (const float*)d_in[2];   // [4096,4096]
  float* out = (float*)d_out;                 // [8,32,64,64]
  float* cadj = (float*)d_ws;                 // [8,4096] scratch (128 KB)

  channel_mean_kernel<<<dim3((B_DIM * N_DIM + 255) / 256), dim3(256), 0, stream>>>(x, cadj);
  gcn_fused_kernel<<<dim3(N_DIM / TM, B_DIM), dim3(BLOCK), 0, stream>>>(x, para, adj, cadj, out);
}

// Round 2
// 181.976 us; speedup vs baseline: 2.2187x; 2.2187x over previous
//
#include <hip/hip_runtime.h>
#include <hip/hip_bf16.h>
#include <math.h>

#define B_DIM 8
#define C_DIM 32
#define N_DIM 4096

typedef short bf16x8 __attribute__((ext_vector_type(8)));   // 8 bf16 in 4 VGPRs
typedef float f32x4 __attribute__((ext_vector_type(4)));

__device__ __forceinline__ ushort f2bf_rne(float f) {
  unsigned u = __float_as_uint(f);
  u += 0x7FFF + ((u >> 16) & 1);   // round-to-nearest-even
  return (ushort)(u >> 16);
}

// Kernel 1: cadj[b,n] = mean_c x[b,c,n]; feab[b,c,n] = bf16(x[b,c,n])
__global__ __launch_bounds__(256) void prep_kernel(const float* __restrict__ x,
                                                   float* __restrict__ cadj,
                                                   ushort* __restrict__ feab) {
  int idx = blockIdx.x * 256 + threadIdx.x;   // 0 .. B*N-1
  int b = idx >> 12;
  int n = idx & (N_DIM - 1);
  const float* p = x + (size_t)b * C_DIM * N_DIM + n;
  ushort* q = feab + (size_t)b * C_DIM * N_DIM + n;
  float s = 0.f;
#pragma unroll
  for (int c = 0; c < C_DIM; ++c) {
    float v = p[(size_t)c * N_DIM];
    s += v;
    q[(size_t)c * N_DIM] = f2bf_rne(v);
  }
  cadj[idx] = s * (1.0f / C_DIM);
}

// Kernel 2: one wave per 16 output columns, full K. No LDS, no barriers.
// out[b,c,m] = relu(para[c,m] * sum_n fea[b,c,n] * adj[n,m] * 2*sigmoid(-|cadj[b,n]-cadj[b,m]|))
__global__ __launch_bounds__(256) void gcn_mfma_kernel(
    const ushort* __restrict__ feab, const float* __restrict__ para,
    const float* __restrict__ adj, const float* __restrict__ cadj,
    float* __restrict__ out) {
  const int lane = threadIdx.x & 63;
  const int wid = threadIdx.x >> 6;
  const int b = blockIdx.y;
  const int colgrp = blockIdx.x * 4 + wid;          // 0..255
  const int col = colgrp * 16 + (lane & 15);        // this lane's output column
  const int quad = lane >> 4;

  const float cm = cadj[b * N_DIM + col];
  const ushort* fb = feab + (size_t)b * C_DIM * N_DIM;
  const float* ckb = cadj + b * N_DIM;

  f32x4 acc0 = {0.f, 0.f, 0.f, 0.f};
  f32x4 acc1 = {0.f, 0.f, 0.f, 0.f};

  // double-buffered register prefetch
  float adjv[2][8];
  float ckv[2][8];
  bf16x8 fa0[2], fa1[2];

#define LOAD_STAGE(kc, s)                                                     \
  {                                                                           \
    int kbase = (kc) * 32 + quad * 8;                                         \
    fa0[s] = *(const bf16x8*)(fb + (lane & 15) * N_DIM + kbase);              \
    fa1[s] = *(const bf16x8*)(fb + (16 + (lane & 15)) * N_DIM + kbase);       \
    *(f32x4*)&ckv[s][0] = *(const f32x4*)(ckb + kbase);                       \
    *(f32x4*)&ckv[s][4] = *(const f32x4*)(ckb + kbase + 4);                   \
    _Pragma("unroll")                                                         \
    for (int j = 0; j < 8; ++j)                                               \
      adjv[s][j] = adj[(size_t)(kbase + j) * N_DIM + col];                    \
  }

  LOAD_STAGE(0, 0)

#pragma unroll 2
  for (int kc = 0; kc < N_DIM / 32; ++kc) {
    const int s = kc & 1;
    if (kc + 1 < N_DIM / 32) LOAD_STAGE(kc + 1, s ^ 1)

    bf16x8 wfrag;
#pragma unroll
    for (int j = 0; j < 8; ++j) {
      float d = ckv[s][j] - cm;
      // 2*sigmoid(-|d|) = 2t/(1+t), t = exp(-|d|)   (even in d: symmetrization is identity)
      float t = __builtin_amdgcn_exp2f(fabsf(d) * -1.44269504f);
      float w = adjv[s][j] * (2.0f * t * __builtin_amdgcn_rcpf(1.0f + t));
      wfrag[j] = (short)f2bf_rne(w);
    }
    acc0 = __builtin_amdgcn_mfma_f32_16x16x32_bf16(fa0[s], wfrag, acc0, 0, 0, 0);
    acc1 = __builtin_amdgcn_mfma_f32_16x16x32_bf16(fa1[s], wfrag, acc1, 0, 0, 0);
  }

  // Epilogue: *para, relu. D layout: col=lane&15, row=quad*4+reg
  float* ob = out + (size_t)b * C_DIM * N_DIM;
#pragma unroll
  for (int r = 0; r < 4; ++r) {
    int row0 = quad * 4 + r;
    int row1 = row0 + 16;
    float v0 = acc0[r] * para[(size_t)row0 * N_DIM + col];
    float v1 = acc1[r] * para[(size_t)row1 * N_DIM + col];
    ob[(size_t)row0 * N_DIM + col] = fmaxf(v0, 0.f);
    ob[(size_t)row1 * N_DIM + col] = fmaxf(v1, 0.f);
  }
}

extern "C" void kernel_launch(void* const* d_in, const int* in_sizes, int n_in,
                              void* d_out, int out_size, void* d_ws, size_t ws_size,
                              hipStream_t stream) {
  const float* x = (const float*)d_in[0];     // [8,32,64,64]
  const float* para = (const float*)d_in[1];  // [1,32,64,64]
  const float* adj = (const float*)d_in[2];   // [4096,4096]
  float* out = (float*)d_out;

  float* cadj = (float*)d_ws;                               // 8*4096 f32 = 128 KB
  ushort* feab = (ushort*)((char*)d_ws + B_DIM * N_DIM * 4);  // 8*32*4096 bf16 = 2 MB

  prep_kernel<<<dim3(B_DIM * N_DIM / 256), dim3(256), 0, stream>>>(x, cadj, feab);
  gcn_mfma_kernel<<<dim3(N_DIM / 64, B_DIM), dim3(256), 0, stream>>>(feab, para, adj, cadj, out);
}